// Round 4
// baseline (313.967 us; speedup 1.0000x reference)
//
#include <hip/hip_runtime.h>

#define T_STEPS 2048
#define B_CH    8192
#define DT_F    0.01f
#define NCHUNK  32
#define CHUNK   (T_STEPS / NCHUNK)   // 64 accumulated steps per chunk
#define WARM    64                   // warm-up steps (multiple of 16); validated at R2
#define TILE    8                    // register-staged timesteps per buffer

__device__ __forceinline__ float fast_rcp(float x)   { return __builtin_amdgcn_rcpf(x); }
__device__ __forceinline__ float fast_rsqrt(float x) { return __builtin_amdgcn_rsqf(x); }
__device__ __forceinline__ float fast_log2(float x)  { return __builtin_amdgcn_logf(x); }

struct Q9 { float q00,q01,q02,q10,q11,q12,q20,q21,q22; };

// EXACT reference GS step (rows normalized every step — R1's passing math).
// Only the log is deferred: P_k *= n_k per step, harvested every 16 steps.
// Products stay in [0.04, 1] over 16 steps — safe in fp32.
// Projections use unnormalized dots with c = d/n0 (inv0 = rsq(n0)^2), which
// is algebraically identical to the normalized-dot projection.
__device__ __forceinline__ void gs_step(float x, float y, float z, Q9& Q,
                                        float& P0, float& P1, float& P2) {
  const float a00 = 0.9f;            // 1 - DT*SIGMA
  const float a01 = 0.1f;            // DT*SIGMA
  const float a11 = 0.99f;           // 1 - DT
  const float a22 = 1.0f - DT_F * (8.0f / 3.0f);
  float a10 = DT_F * (28.0f - z);
  float a12 = -DT_F * x;
  float a20 = DT_F * y;
  float a21 = DT_F * x;

  // M = A * Q  (A[0][2] == 0)
  float m00 = a00*Q.q00 + a01*Q.q10;
  float m01 = a00*Q.q01 + a01*Q.q11;
  float m02 = a00*Q.q02 + a01*Q.q12;
  float m10 = a10*Q.q00 + a11*Q.q10 + a12*Q.q20;
  float m11 = a10*Q.q01 + a11*Q.q11 + a12*Q.q21;
  float m12 = a10*Q.q02 + a11*Q.q12 + a12*Q.q22;
  float m20 = a20*Q.q00 + a21*Q.q10 + a22*Q.q20;
  float m21 = a20*Q.q01 + a21*Q.q11 + a22*Q.q21;
  float m22 = a20*Q.q02 + a21*Q.q12 + a22*Q.q22;

  // independent dots
  float n0 = m00*m00 + m01*m01 + m02*m02;
  float d1 = m00*m10 + m01*m11 + m02*m12;
  float d2 = m00*m20 + m01*m21 + m02*m22;

  float i0 = fast_rsqrt(n0);
  float inv0 = i0 * i0;
  P0 *= n0;
  Q.q00 = m00*i0; Q.q01 = m01*i0; Q.q02 = m02*i0;

  float c1 = d1 * inv0;
  float r10 = m10 - c1*m00, r11 = m11 - c1*m01, r12 = m12 - c1*m02;
  float c2 = d2 * inv0;
  float r20 = m20 - c2*m00, r21 = m21 - c2*m01, r22 = m22 - c2*m02;

  float n1 = r10*r10 + r11*r11 + r12*r12;
  float d3 = r10*r20 + r11*r21 + r12*r22;
  float i1 = fast_rsqrt(n1);
  float inv1 = i1 * i1;
  P1 *= n1;
  Q.q10 = r10*i1; Q.q11 = r11*i1; Q.q12 = r12*i1;

  float c3 = d3 * inv1;
  float s20 = r20 - c3*r10, s21 = r21 - c3*r11, s22 = r22 - c3*r12;
  float n2 = s20*s20 + s21*s21 + s22*s22;
  float i2 = fast_rsqrt(n2);
  P2 *= n2;
  Q.q20 = s20*i2; Q.q21 = s21*i2; Q.q22 = s22*i2;
}

// Grid: (32, NCHUNK) x 256. One thread per (chain, chunk). Warm chunks re-run
// WARM steps from identity (discarded via snapshot-subtract at a harvest
// boundary), then accumulate CHUNK steps. Chunk 0 is exact; row 0 is exact
// always (n0 = 0.82 independent of Q).
__global__ __launch_bounds__(256, 4) void lyap_chunk_kernel(const float* __restrict__ traj,
                                                            float* __restrict__ ws) {
  const int b = blockIdx.x * 256 + threadIdx.x;      // chain id
  const int chunk = blockIdx.y;
  const int warm = (chunk == 0) ? 0 : WARM;
  const int warmPer = warm / (2 * TILE);             // 16-step warm periods: 0 or 4
  const int nper = (CHUNK + warm) / (2 * TILE);      // 4 or 8
  const float* __restrict__ p =
      traj + (size_t)(chunk * CHUNK - warm) * (3 * B_CH) + b;

  float sA[TILE][3], sB[TILE][3];
#pragma unroll
  for (int i = 0; i < TILE; ++i) {
    sA[i][0] = p[(i*3 + 0) * B_CH];
    sA[i][1] = p[(i*3 + 1) * B_CH];
    sA[i][2] = p[(i*3 + 2) * B_CH];
  }

  Q9 Q = {1.f,0.f,0.f, 0.f,1.f,0.f, 0.f,0.f,1.f};
  float S0 = 0.f, S1 = 0.f, S2 = 0.f;
  float B0 = 0.f, B1 = 0.f, B2 = 0.f;
  float P0 = 1.f, P1 = 1.f, P2 = 1.f;

  for (int per = 0; per < nper; ++per) {
    // invariant: tile 2*per resident in sA; S fully harvested, P == 1
    if (per == warmPer) { B0 = S0; B1 = S1; B2 = S2; }  // chunk start snapshot
    {  // prefetch tile 2*per+1 into B (always exists)
      const float* pt = p + (size_t)(2*per + 1) * (TILE*3*B_CH);
#pragma unroll
      for (int i = 0; i < TILE; ++i) {
        sB[i][0] = pt[(i*3 + 0) * B_CH];
        sB[i][1] = pt[(i*3 + 1) * B_CH];
        sB[i][2] = pt[(i*3 + 2) * B_CH];
      }
    }
#pragma unroll
    for (int i = 0; i < TILE; ++i)
      gs_step(sA[i][0], sA[i][1], sA[i][2], Q, P0, P1, P2);

    if (per + 1 < nper) {  // prefetch tile 2*per+2 into A
      const float* pt = p + (size_t)(2*per + 2) * (TILE*3*B_CH);
#pragma unroll
      for (int i = 0; i < TILE; ++i) {
        sA[i][0] = pt[(i*3 + 0) * B_CH];
        sA[i][1] = pt[(i*3 + 1) * B_CH];
        sA[i][2] = pt[(i*3 + 2) * B_CH];
      }
    }
#pragma unroll
    for (int i = 0; i < TILE; ++i)
      gs_step(sB[i][0], sB[i][1], sB[i][2], Q, P0, P1, P2);

    // harvest deferred logs (every 16 steps)
    S0 += fast_log2(P0); P0 = 1.f;
    S1 += fast_log2(P1); P1 = 1.f;
    S2 += fast_log2(P2); P2 = 1.f;
  }

  ws[(chunk*3 + 0) * B_CH + b] = S0 - B0;
  ws[(chunk*3 + 1) * B_CH + b] = S1 - B1;
  ws[(chunk*3 + 2) * B_CH + b] = S2 - B2;
}

__global__ __launch_bounds__(256) void lyap_reduce_kernel(const float* __restrict__ ws,
                                                          float* __restrict__ out) {
  const int i = blockIdx.x * 256 + threadIdx.x;      // 0 .. 3*B_CH
  float s = 0.f;
#pragma unroll
  for (int c = 0; c < NCHUNK; ++c) s += ws[c * 3 * B_CH + i];
  const float scale = 0.5f * 0.69314718055994531f / (T_STEPS * DT_F);
  out[i] = s * scale;
}

extern "C" void kernel_launch(void* const* d_in, const int* in_sizes, int n_in,
                              void* d_out, int out_size, void* d_ws, size_t ws_size,
                              hipStream_t stream) {
  (void)in_sizes; (void)n_in; (void)out_size; (void)ws_size;
  const float* traj = (const float*)d_in[0];
  float* out = (float*)d_out;
  float* ws  = (float*)d_ws;   // NCHUNK*3*B_CH*4 = 3.1 MB

  lyap_chunk_kernel<<<dim3(B_CH / 256, NCHUNK), dim3(256), 0, stream>>>(traj, ws);
  lyap_reduce_kernel<<<dim3(3 * B_CH / 256), dim3(256), 0, stream>>>(ws, out);
}

// Round 5
// 312.406 us; speedup vs baseline: 1.0050x; 1.0050x over previous
//
#include <hip/hip_runtime.h>

#define T_STEPS 2048
#define B_CH    8192
#define DT_F    0.01f
#define NCHUNK  32
#define CHUNK   (T_STEPS / NCHUNK)   // 64 accumulated steps per chunk
#define WARM    64                   // warm-up steps (validated: absmax 0.0 at R3)
#define TILE    8                    // register-staged timesteps per buffer

__device__ __forceinline__ float fast_rsqrt(float x) { return __builtin_amdgcn_rsqf(x); }
__device__ __forceinline__ float fast_log2(float x)  { return __builtin_amdgcn_logf(x); }

struct Q9 { float q00,q01,q02,q10,q11,q12,q20,q21,q22; };

// EXACT reference GS step (rows normalized every step). Only the log is
// deferred: P_k *= n_k per step, harvested every 16 steps (P in [0.04,1]).
// Projection c = d/n0 via inv0 = rsq(n0)^2 — algebraically identical to the
// reference's normalized-dot projection.
__device__ __forceinline__ void gs_step(float x, float y, float z, Q9& Q,
                                        float& P0, float& P1, float& P2) {
  const float a00 = 0.9f;            // 1 - DT*SIGMA
  const float a01 = 0.1f;            // DT*SIGMA
  const float a11 = 0.99f;           // 1 - DT
  const float a22 = 1.0f - DT_F * (8.0f / 3.0f);
  float a10 = DT_F * (28.0f - z);
  float a12 = -DT_F * x;
  float a20 = DT_F * y;
  float a21 = DT_F * x;

  // M = A * Q  (A[0][2] == 0)
  float m00 = a00*Q.q00 + a01*Q.q10;
  float m01 = a00*Q.q01 + a01*Q.q11;
  float m02 = a00*Q.q02 + a01*Q.q12;
  float m10 = a10*Q.q00 + a11*Q.q10 + a12*Q.q20;
  float m11 = a10*Q.q01 + a11*Q.q11 + a12*Q.q21;
  float m12 = a10*Q.q02 + a11*Q.q12 + a12*Q.q22;
  float m20 = a20*Q.q00 + a21*Q.q10 + a22*Q.q20;
  float m21 = a20*Q.q01 + a21*Q.q11 + a22*Q.q21;
  float m22 = a20*Q.q02 + a21*Q.q12 + a22*Q.q22;

  float n0 = m00*m00 + m01*m01 + m02*m02;
  float d1 = m00*m10 + m01*m11 + m02*m12;
  float d2 = m00*m20 + m01*m21 + m02*m22;

  float i0 = fast_rsqrt(n0);
  float inv0 = i0 * i0;
  P0 *= n0;
  Q.q00 = m00*i0; Q.q01 = m01*i0; Q.q02 = m02*i0;

  float c1 = d1 * inv0;
  float r10 = m10 - c1*m00, r11 = m11 - c1*m01, r12 = m12 - c1*m02;
  float c2 = d2 * inv0;
  float r20 = m20 - c2*m00, r21 = m21 - c2*m01, r22 = m22 - c2*m02;

  float n1 = r10*r10 + r11*r11 + r12*r12;
  float d3 = r10*r20 + r11*r21 + r12*r22;
  float i1 = fast_rsqrt(n1);
  float inv1 = i1 * i1;
  P1 *= n1;
  Q.q10 = r10*i1; Q.q11 = r11*i1; Q.q12 = r12*i1;

  float c3 = d3 * inv1;
  float s20 = r20 - c3*r10, s21 = r21 - c3*r11, s22 = r22 - c3*r12;
  float n2 = s20*s20 + s21*s21 + s22*s22;
  float i2 = fast_rsqrt(n2);
  P2 *= n2;
  Q.q20 = s20*i2; Q.q21 = s21*i2; Q.q22 = s22*i2;
}

// Grid: (32, NCHUNK) x 256. One thread per (chain, chunk).
// amdgpu_waves_per_eu(4,4): pin occupancy at exactly 4 waves/EU so the
// allocator uses the full 128-VGPR budget instead of squeezing to 64 and
// breaking the 24-load prefetch pipeline (R3: VGPR_Count=64, loads sunk to
// use => exposed memory latency every few steps).
__global__ __attribute__((amdgpu_waves_per_eu(4, 4)))
__launch_bounds__(256) void lyap_chunk_kernel(const float* __restrict__ traj,
                                              float* __restrict__ ws) {
  const int b = blockIdx.x * 256 + threadIdx.x;      // chain id
  const int chunk = blockIdx.y;
  const int warm = (chunk == 0) ? 0 : WARM;
  const int warmPer = warm / (2 * TILE);             // 16-step warm periods: 0 or 4
  const int nper = (CHUNK + warm) / (2 * TILE);      // 4 or 8
  const float* __restrict__ p =
      traj + (size_t)(chunk * CHUNK - warm) * (3 * B_CH) + b;

  float sA[TILE][3], sB[TILE][3];
#pragma unroll
  for (int i = 0; i < TILE; ++i) {
    sA[i][0] = p[(i*3 + 0) * B_CH];
    sA[i][1] = p[(i*3 + 1) * B_CH];
    sA[i][2] = p[(i*3 + 2) * B_CH];
  }

  Q9 Q = {1.f,0.f,0.f, 0.f,1.f,0.f, 0.f,0.f,1.f};
  float S0 = 0.f, S1 = 0.f, S2 = 0.f;
  float B0 = 0.f, B1 = 0.f, B2 = 0.f;
  float P0 = 1.f, P1 = 1.f, P2 = 1.f;

  for (int per = 0; per < nper; ++per) {
    // invariant: tile 2*per resident in sA; S fully harvested, P == 1
    if (per == warmPer) { B0 = S0; B1 = S1; B2 = S2; }  // chunk start snapshot
    {  // prefetch tile 2*per+1 into B (always exists)
      const float* pt = p + (size_t)(2*per + 1) * (TILE*3*B_CH);
#pragma unroll
      for (int i = 0; i < TILE; ++i) {
        sB[i][0] = pt[(i*3 + 0) * B_CH];
        sB[i][1] = pt[(i*3 + 1) * B_CH];
        sB[i][2] = pt[(i*3 + 2) * B_CH];
      }
    }
#pragma unroll
    for (int i = 0; i < TILE; ++i)
      gs_step(sA[i][0], sA[i][1], sA[i][2], Q, P0, P1, P2);

    if (per + 1 < nper) {  // prefetch tile 2*per+2 into A
      const float* pt = p + (size_t)(2*per + 2) * (TILE*3*B_CH);
#pragma unroll
      for (int i = 0; i < TILE; ++i) {
        sA[i][0] = pt[(i*3 + 0) * B_CH];
        sA[i][1] = pt[(i*3 + 1) * B_CH];
        sA[i][2] = pt[(i*3 + 2) * B_CH];
      }
    }
#pragma unroll
    for (int i = 0; i < TILE; ++i)
      gs_step(sB[i][0], sB[i][1], sB[i][2], Q, P0, P1, P2);

    // harvest deferred logs (every 16 steps)
    S0 += fast_log2(P0); P0 = 1.f;
    S1 += fast_log2(P1); P1 = 1.f;
    S2 += fast_log2(P2); P2 = 1.f;
  }

  ws[(chunk*3 + 0) * B_CH + b] = S0 - B0;
  ws[(chunk*3 + 1) * B_CH + b] = S1 - B1;
  ws[(chunk*3 + 2) * B_CH + b] = S2 - B2;
}

__global__ __launch_bounds__(256) void lyap_reduce_kernel(const float* __restrict__ ws,
                                                          float* __restrict__ out) {
  const int i = blockIdx.x * 256 + threadIdx.x;      // 0 .. 3*B_CH
  float s = 0.f;
#pragma unroll
  for (int c = 0; c < NCHUNK; ++c) s += ws[c * 3 * B_CH + i];
  const float scale = 0.5f * 0.69314718055994531f / (T_STEPS * DT_F);
  out[i] = s * scale;
}

extern "C" void kernel_launch(void* const* d_in, const int* in_sizes, int n_in,
                              void* d_out, int out_size, void* d_ws, size_t ws_size,
                              hipStream_t stream) {
  (void)in_sizes; (void)n_in; (void)out_size; (void)ws_size;
  const float* traj = (const float*)d_in[0];
  float* out = (float*)d_out;
  float* ws  = (float*)d_ws;   // NCHUNK*3*B_CH*4 = 3.1 MB

  lyap_chunk_kernel<<<dim3(B_CH / 256, NCHUNK), dim3(256), 0, stream>>>(traj, ws);
  lyap_reduce_kernel<<<dim3(3 * B_CH / 256), dim3(256), 0, stream>>>(ws, out);
}